// Round 15
// baseline (4237.426 us; speedup 1.0000x reference)
//
#include <hip/hip_runtime.h>

#define B_ 16
#define S_ 4096
#define D_ 256
#define H_ 256

typedef _Float16 h2 __attribute__((ext_vector_type(2)));
typedef _Float16 h4 __attribute__((ext_vector_type(4)));
typedef _Float16 h8 __attribute__((ext_vector_type(8)));
typedef _Float16 h8v __attribute__((ext_vector_type(8)));
typedef float f4 __attribute__((ext_vector_type(4)));

static __device__ __forceinline__ float fdot2f(h2 a, h2 b, float c) {
    return __builtin_amdgcn_fdot2(a, b, c, false);
}

template <int CTRL>
static __device__ __forceinline__ float dpp_qp(float v) {
    int r = __builtin_amdgcn_update_dpp(0, __float_as_int(v), CTRL, 0xF, 0xF, true);
    return __int_as_float(r);
}
#define DPP_XOR1 0xB1   // quad_perm [1,0,3,2]
#define DPP_XOR2 0x4E   // quad_perm [2,3,0,1]

// LDS-only barrier: drain LDS ops, NOT vmcnt (T4).
static __device__ __forceinline__ void lds_barrier() {
    asm volatile("s_waitcnt lgkmcnt(0)" ::: "memory");
    __builtin_amdgcn_s_barrier();
}

// swizzled f16-index for h element i in a 256-entry LDS buffer (R4/R8-verified).
static __device__ __forceinline__ int swz(int i) {
    const int s = i >> 6, r = (i >> 3) & 7, e = i & 7;
    return 64 * s + 8 * ((r + 2 * s) & 7) + e;
}

// Kernel 1: xp = x @ Wx + b via MFMA f16 (f32 accumulate) — round-14 version
// (verified: dropped xproj from ~186 us to noise level).
__global__ __launch_bounds__(256, 1) void xproj_kernel(
    const float* __restrict__ x, const float* __restrict__ Wx,
    const float* __restrict__ bias, float* __restrict__ out)
{
    __shared__ __align__(16) _Float16 xs[16 * 272];
    const int tid = threadIdx.x;
    const int l   = tid & 63;
    const int wav = tid >> 6;      // 0..3
    const int lc  = l & 15;
    const int kg  = l >> 4;        // 0..3
    const long long row0 = (long long)blockIdx.x * 256;

    h8v bf[4][8];
    #pragma unroll
    for (int nt = 0; nt < 4; ++nt) {
        const int j = 64 * wav + 16 * nt + lc;
        #pragma unroll
        for (int ks = 0; ks < 8; ++ks) {
            #pragma unroll
            for (int e = 0; e < 8; ++e)
                bf[nt][ks][e] = (_Float16)Wx[(32 * ks + 8 * kg + e) * H_ + j];
        }
    }
    float bvv[4];
    #pragma unroll
    for (int nt = 0; nt < 4; ++nt)
        bvv[nt] = bias[64 * wav + 16 * nt + lc];

    f4 pre[4];
    #pragma unroll
    for (int k4 = 0; k4 < 4; ++k4)
        pre[k4] = *(const f4*)&x[(row0 + wav + 4 * k4) * D_ + 4 * l];

    for (int it = 0; it < 16; ++it) {
        const long long r0 = row0 + it * 16;

        __syncthreads();
        #pragma unroll
        for (int k4 = 0; k4 < 4; ++k4) {
            h4 hv;
            hv[0] = (_Float16)pre[k4].x;
            hv[1] = (_Float16)pre[k4].y;
            hv[2] = (_Float16)pre[k4].z;
            hv[3] = (_Float16)pre[k4].w;
            *(h4*)&xs[(wav + 4 * k4) * 272 + 4 * l] = hv;
        }
        __syncthreads();

        if (it + 1 < 16) {
            const long long rn = row0 + (it + 1) * 16;
            #pragma unroll
            for (int k4 = 0; k4 < 4; ++k4)
                pre[k4] = *(const f4*)&x[(rn + wav + 4 * k4) * D_ + 4 * l];
        }

        f4 acc[4];
        #pragma unroll
        for (int nt = 0; nt < 4; ++nt)
            acc[nt] = (f4){0.f, 0.f, 0.f, 0.f};

        #pragma unroll
        for (int ks = 0; ks < 8; ++ks) {
            h8v af = *(const h8v*)&xs[lc * 272 + 32 * ks + 8 * kg];
            acc[0] = __builtin_amdgcn_mfma_f32_16x16x32_f16(af, bf[0][ks], acc[0], 0, 0, 0);
            acc[1] = __builtin_amdgcn_mfma_f32_16x16x32_f16(af, bf[1][ks], acc[1], 0, 0, 0);
            acc[2] = __builtin_amdgcn_mfma_f32_16x16x32_f16(af, bf[2][ks], acc[2], 0, 0, 0);
            acc[3] = __builtin_amdgcn_mfma_f32_16x16x32_f16(af, bf[3][ks], acc[3], 0, 0, 0);
        }

        #pragma unroll
        for (int nt = 0; nt < 4; ++nt) {
            const int j = 64 * wav + 16 * nt + lc;
            #pragma unroll
            for (int r = 0; r < 4; ++r)
                out[(r0 + 4 * kg + r) * H_ + j] = acc[nt][r] + bvv[nt];
        }
    }
}

// Kernel 2: DUAL-BATCH scan. 8 blocks x 256 threads; each block runs TWO
// independent recurrences (batches 2*blk, 2*blk+1) through the same wave
// instruction stream, sharing the Wh registers (w[4][32] loaded once).
// Batch B's dot2 issue hides batch A's ds_read/chain latency; the per-step
// serial overhead (reduce->tanh->publish->barrier) amortizes over 2 steps.
// Structure per batch = round-8 (best measured): split-K x4, DPP quad
// reduce, swizzled h LDS, xp ring distance 4, lgkm-only barrier.
__global__ __launch_bounds__(256, 1) void scan_kernel(
    const float* __restrict__ Wh, const float* __restrict__ state0,
    float* __restrict__ out)
{
    __shared__ __align__(16) _Float16 hbufA[2][H_];
    __shared__ __align__(16) _Float16 hbufB[2][H_];
    const int tid = threadIdx.x;
    const int s = tid & 3;          // i-slice
    const int q = tid >> 2;         // j-group
    const bool o1 = (s & 1) != 0;
    const bool o2 = (s & 2) != 0;
    const int bA = blockIdx.x * 2;
    const int bB = bA + 1;

    // Shared weights: W[i][j], i in [64s,64s+64), j in [4q,4q+4). 128 VGPRs.
    h2 w[4][32];
    #pragma unroll
    for (int jj = 0; jj < 4; ++jj) {
        const int j = 4 * q + jj;
        #pragma unroll
        for (int ii = 0; ii < 32; ++ii) {
            const int i = 64 * s + 2 * ii;
            h2 p;
            p[0] = (_Float16)Wh[(long long)i * H_ + j];
            p[1] = (_Float16)Wh[(long long)(i + 1) * H_ + j];
            w[jj][ii] = p;
        }
    }

    hbufA[0][swz(tid)] = (_Float16)state0[bA * H_ + tid];
    hbufB[0][swz(tid)] = (_Float16)state0[bB * H_ + tid];

    float* __restrict__ outA = out + (long long)bA * S_ * H_;
    float* __restrict__ outB = out + (long long)bB * S_ * H_;

    float xrA[4], xrB[4];
    #pragma unroll
    for (int k = 0; k < 4; ++k) {
        xrA[k] = outA[(long long)k * H_ + tid];
        xrB[k] = outB[(long long)k * H_ + tid];
    }
    __syncthreads();

    #pragma unroll 2
    for (int st = 0; st < S_; ++st) {
        const int p = st & 1;
        const _Float16* hbA = hbufA[p];
        const _Float16* hbB = hbufB[p];

        // issue all 16 h-reads up front (A's latency hides under B's issue)
        h8 hvA[8], hvB[8];
        #pragma unroll
        for (int r = 0; r < 8; ++r)
            hvA[r] = *(const h8*)&hbA[64 * s + 8 * ((r + 2 * s) & 7)];
        #pragma unroll
        for (int r = 0; r < 8; ++r)
            hvB[r] = *(const h8*)&hbB[64 * s + 8 * ((r + 2 * s) & 7)];

        float aA0 = 0.f, aA1 = 0.f, aA2 = 0.f, aA3 = 0.f;
        float aB0 = 0.f, aB1 = 0.f, aB2 = 0.f, aB3 = 0.f;
        #pragma unroll
        for (int r = 0; r < 8; ++r) {
            union { h8 v; h2 pr[4]; } uA, uB;
            uA.v = hvA[r];
            uB.v = hvB[r];
            #pragma unroll
            for (int m = 0; m < 4; ++m) {
                const int ii = 4 * r + m;
                aA0 = fdot2f(uA.pr[m], w[0][ii], aA0);
                aA1 = fdot2f(uA.pr[m], w[1][ii], aA1);
                aA2 = fdot2f(uA.pr[m], w[2][ii], aA2);
                aA3 = fdot2f(uA.pr[m], w[3][ii], aA3);
                aB0 = fdot2f(uB.pr[m], w[0][ii], aB0);
                aB1 = fdot2f(uB.pr[m], w[1][ii], aB1);
                aB2 = fdot2f(uB.pr[m], w[2][ii], aB2);
                aB3 = fdot2f(uB.pr[m], w[3][ii], aB3);
            }
        }

        // DPP quad reduce-scatter, batch A
        float vA1 = o1 ? aA1 : aA0, sA1 = o1 ? aA0 : aA1;
        float vA2 = o1 ? aA3 : aA2, sA2 = o1 ? aA2 : aA3;
        vA1 += dpp_qp<DPP_XOR1>(sA1);
        vA2 += dpp_qp<DPP_XOR1>(sA2);
        float vA  = o2 ? vA2 : vA1, dA = o2 ? vA1 : vA2;
        vA += dpp_qp<DPP_XOR2>(dA);
        // batch B
        float vB1 = o1 ? aB1 : aB0, sB1 = o1 ? aB0 : aB1;
        float vB2 = o1 ? aB3 : aB2, sB2 = o1 ? aB2 : aB3;
        vB1 += dpp_qp<DPP_XOR1>(sB1);
        vB2 += dpp_qp<DPP_XOR1>(sB2);
        float vB  = o2 ? vB2 : vB1, dB = o2 ? vB1 : vB2;
        vB += dpp_qp<DPP_XOR2>(dB);

        const float preA = vA + xrA[st & 3];
        const float preB = vB + xrB[st & 3];
        const float eA = __builtin_amdgcn_exp2f(preA * 2.8853900817779268f);
        const float eB = __builtin_amdgcn_exp2f(preB * 2.8853900817779268f);
        const float hnA = fmaf(-2.f, __builtin_amdgcn_rcpf(eA + 1.f), 1.f);
        const float hnB = fmaf(-2.f, __builtin_amdgcn_rcpf(eB + 1.f), 1.f);

        outA[(long long)st * H_ + tid] = hnA;      // stays in flight
        outB[(long long)st * H_ + tid] = hnB;
        hbufA[p ^ 1][swz(tid)] = (_Float16)hnA;    // publish h for t+1
        hbufB[p ^ 1][swz(tid)] = (_Float16)hnB;

        const int nt = st + 4;
        if (nt < S_) {
            xrA[st & 3] = outA[(long long)nt * H_ + tid];
            xrB[st & 3] = outB[(long long)nt * H_ + tid];
        }
        lds_barrier();   // lgkmcnt(0) + s_barrier — no vmcnt drain
    }
}

extern "C" void kernel_launch(void* const* d_in, const int* in_sizes, int n_in,
                              void* d_out, int out_size, void* d_ws, size_t ws_size,
                              hipStream_t stream) {
    const float* x  = (const float*)d_in[0];   // [B,S,D]
    const float* s0 = (const float*)d_in[1];   // [B,H]
    const float* Wx = (const float*)d_in[2];   // [D,H]
    const float* Wh = (const float*)d_in[3];   // [H,H]
    const float* bv = (const float*)d_in[4];   // [H]
    float* out = (float*)d_out;                // [B,S,H]

    xproj_kernel<<<dim3((B_ * S_) / 256), dim3(256), 0, stream>>>(x, Wx, bv, out);
    scan_kernel<<<dim3(B_ / 2), dim3(256), 0, stream>>>(Wh, s0, out);
}

// Round 16
// 2753.180 us; speedup vs baseline: 1.5391x; 1.5391x over previous
//
#include <hip/hip_runtime.h>

#define B_ 16
#define S_ 4096
#define D_ 256
#define H_ 256

typedef _Float16 h2 __attribute__((ext_vector_type(2)));
typedef _Float16 h4 __attribute__((ext_vector_type(4)));
typedef _Float16 h8 __attribute__((ext_vector_type(8)));
typedef _Float16 h8v __attribute__((ext_vector_type(8)));
typedef float f4 __attribute__((ext_vector_type(4)));

static __device__ __forceinline__ float fdot2f(h2 a, h2 b, float c) {
    return __builtin_amdgcn_fdot2(a, b, c, false);
}

template <int CTRL>
static __device__ __forceinline__ float dpp_qp(float v) {
    int r = __builtin_amdgcn_update_dpp(0, __float_as_int(v), CTRL, 0xF, 0xF, true);
    return __int_as_float(r);
}
#define DPP_XOR1 0xB1   // quad_perm [1,0,3,2]
#define DPP_XOR2 0x4E   // quad_perm [2,3,0,1]

// LDS-only barrier: drain LDS ops, NOT vmcnt (T4).
static __device__ __forceinline__ void lds_barrier() {
    asm volatile("s_waitcnt lgkmcnt(0)" ::: "memory");
    __builtin_amdgcn_s_barrier();
}

// swizzled f16-index for h element i in a 256-entry LDS buffer (R4/R8-verified).
static __device__ __forceinline__ int swz(int i) {
    const int s = i >> 6, r = (i >> 3) & 7, e = i & 7;
    return 64 * s + 8 * ((r + 2 * s) & 7) + e;
}

// Kernel 1: xp = x @ Wx + b via MFMA f16 (round-14 version, verified).
__global__ __launch_bounds__(256, 1) void xproj_kernel(
    const float* __restrict__ x, const float* __restrict__ Wx,
    const float* __restrict__ bias, float* __restrict__ out)
{
    __shared__ __align__(16) _Float16 xs[16 * 272];
    const int tid = threadIdx.x;
    const int l   = tid & 63;
    const int wav = tid >> 6;      // 0..3
    const int lc  = l & 15;
    const int kg  = l >> 4;        // 0..3
    const long long row0 = (long long)blockIdx.x * 256;

    h8v bf[4][8];
    #pragma unroll
    for (int nt = 0; nt < 4; ++nt) {
        const int j = 64 * wav + 16 * nt + lc;
        #pragma unroll
        for (int ks = 0; ks < 8; ++ks) {
            #pragma unroll
            for (int e = 0; e < 8; ++e)
                bf[nt][ks][e] = (_Float16)Wx[(32 * ks + 8 * kg + e) * H_ + j];
        }
    }
    float bvv[4];
    #pragma unroll
    for (int nt = 0; nt < 4; ++nt)
        bvv[nt] = bias[64 * wav + 16 * nt + lc];

    f4 pre[4];
    #pragma unroll
    for (int k4 = 0; k4 < 4; ++k4)
        pre[k4] = *(const f4*)&x[(row0 + wav + 4 * k4) * D_ + 4 * l];

    for (int it = 0; it < 16; ++it) {
        const long long r0 = row0 + it * 16;

        __syncthreads();
        #pragma unroll
        for (int k4 = 0; k4 < 4; ++k4) {
            h4 hv;
            hv[0] = (_Float16)pre[k4].x;
            hv[1] = (_Float16)pre[k4].y;
            hv[2] = (_Float16)pre[k4].z;
            hv[3] = (_Float16)pre[k4].w;
            *(h4*)&xs[(wav + 4 * k4) * 272 + 4 * l] = hv;
        }
        __syncthreads();

        if (it + 1 < 16) {
            const long long rn = row0 + (it + 1) * 16;
            #pragma unroll
            for (int k4 = 0; k4 < 4; ++k4)
                pre[k4] = *(const f4*)&x[(rn + wav + 4 * k4) * D_ + 4 * l];
        }

        f4 acc[4];
        #pragma unroll
        for (int nt = 0; nt < 4; ++nt)
            acc[nt] = (f4){0.f, 0.f, 0.f, 0.f};

        #pragma unroll
        for (int ks = 0; ks < 8; ++ks) {
            h8v af = *(const h8v*)&xs[lc * 272 + 32 * ks + 8 * kg];
            acc[0] = __builtin_amdgcn_mfma_f32_16x16x32_f16(af, bf[0][ks], acc[0], 0, 0, 0);
            acc[1] = __builtin_amdgcn_mfma_f32_16x16x32_f16(af, bf[1][ks], acc[1], 0, 0, 0);
            acc[2] = __builtin_amdgcn_mfma_f32_16x16x32_f16(af, bf[2][ks], acc[2], 0, 0, 0);
            acc[3] = __builtin_amdgcn_mfma_f32_16x16x32_f16(af, bf[3][ks], acc[3], 0, 0, 0);
        }

        #pragma unroll
        for (int nt = 0; nt < 4; ++nt) {
            const int j = 64 * wav + 16 * nt + lc;
            #pragma unroll
            for (int r = 0; r < 4; ++r)
                out[(r0 + 4 * kg + r) * H_ + j] = acc[nt][r] + bvv[nt];
        }
    }
}

// Kernel 2: DUAL-BATCH scan via WAVE-GROUP split (pressure-neutral).
// 8 blocks x 512 threads. tid<256 -> batch 2*blk (half 0), tid>=256 ->
// batch 2*blk+1 (half 1). Each half executes exactly the round-8 structure
// (identical per-thread register profile: w[4][32], 8 ds_read_b128, 128
// dot2, DPP quad reduce, xp ring dist 4) on its own double-buffered h LDS.
// Wave->SIMD round-robin puts one batch-A wave + one batch-B wave on each
// SIMD: independent chains overlap, shared lgkm-only barrier per step.
__global__ __launch_bounds__(512, 1) void scan_kernel(
    const float* __restrict__ Wh, const float* __restrict__ state0,
    float* __restrict__ out)
{
    __shared__ __align__(16) _Float16 hbuf[2][2][H_];   // [half][buf][pos]
    const int tid0 = threadIdx.x;
    const int half = tid0 >> 8;     // 0 or 1
    const int tid  = tid0 & 255;
    const int s = tid & 3;          // i-slice
    const int q = tid >> 2;         // j-group
    const int b = blockIdx.x * 2 + half;
    const bool o1 = (s & 1) != 0;
    const bool o2 = (s & 2) != 0;

    // W[i][j] for i in [64s,64s+64), j in [4q,4q+4), packed as h2 i-pairs.
    h2 w[4][32];
    #pragma unroll
    for (int jj = 0; jj < 4; ++jj) {
        const int j = 4 * q + jj;
        #pragma unroll
        for (int ii = 0; ii < 32; ++ii) {
            const int i = 64 * s + 2 * ii;
            h2 p;
            p[0] = (_Float16)Wh[(long long)i * H_ + j];
            p[1] = (_Float16)Wh[(long long)(i + 1) * H_ + j];
            w[jj][ii] = p;
        }
    }

    hbuf[half][0][swz(tid)] = (_Float16)state0[b * H_ + tid];

    float* __restrict__ outb = out + (long long)b * S_ * H_;

    // xp prefetch ring, distance 4 (static indices via unroll-4)
    float xr[4];
    #pragma unroll
    for (int k = 0; k < 4; ++k)
        xr[k] = outb[(long long)k * H_ + tid];
    __syncthreads();

    // chunk r holds h[64s+8r .. +8] at f16-pos 64s + 8*((r+2s)&7)
    #pragma unroll 4
    for (int st = 0; st < S_; ++st) {
        const int p = st & 1;
        const _Float16* hb = hbuf[half][p];

        h8 hv[8];
        #pragma unroll
        for (int r = 0; r < 8; ++r)
            hv[r] = *(const h8*)&hb[64 * s + 8 * ((r + 2 * s) & 7)];

        float acc0 = 0.f, acc1 = 0.f, acc2 = 0.f, acc3 = 0.f;
        #pragma unroll
        for (int r = 0; r < 8; ++r) {
            union { h8 v; h2 pr[4]; } u;
            u.v = hv[r];
            #pragma unroll
            for (int m = 0; m < 4; ++m) {
                const int ii = 4 * r + m;
                acc0 = fdot2f(u.pr[m], w[0][ii], acc0);
                acc1 = fdot2f(u.pr[m], w[1][ii], acc1);
                acc2 = fdot2f(u.pr[m], w[2][ii], acc2);
                acc3 = fdot2f(u.pr[m], w[3][ii], acc3);
            }
        }

        // reduce-scatter across the 4 slice-threads (pure VALU DPP)
        float vA = o1 ? acc1 : acc0;
        float vB = o1 ? acc3 : acc2;
        float sA = o1 ? acc0 : acc1;
        float sB = o1 ? acc2 : acc3;
        vA += dpp_qp<DPP_XOR1>(sA);
        vB += dpp_qp<DPP_XOR1>(sB);
        float v   = o2 ? vB : vA;
        float snd = o2 ? vA : vB;
        v += dpp_qp<DPP_XOR2>(snd);
        // v = full dot for j = 4q + s = tid

        const float pre = v + xr[st & 3];
        const float e = __builtin_amdgcn_exp2f(pre * 2.8853900817779268f);
        const float hn = fmaf(-2.f, __builtin_amdgcn_rcpf(e + 1.f), 1.f);

        outb[(long long)st * H_ + tid] = hn;            // stays in flight
        hbuf[half][p ^ 1][swz(tid)] = (_Float16)hn;     // publish h for t+1

        const int nt = st + 4;
        xr[st & 3] = (nt < S_) ? outb[(long long)nt * H_ + tid] : 0.f;
        lds_barrier();   // lgkmcnt(0) + s_barrier — no vmcnt drain
    }
}

extern "C" void kernel_launch(void* const* d_in, const int* in_sizes, int n_in,
                              void* d_out, int out_size, void* d_ws, size_t ws_size,
                              hipStream_t stream) {
    const float* x  = (const float*)d_in[0];   // [B,S,D]
    const float* s0 = (const float*)d_in[1];   // [B,H]
    const float* Wx = (const float*)d_in[2];   // [D,H]
    const float* Wh = (const float*)d_in[3];   // [H,H]
    const float* bv = (const float*)d_in[4];   // [H]
    float* out = (float*)d_out;                // [B,S,H]

    xproj_kernel<<<dim3((B_ * S_) / 256), dim3(256), 0, stream>>>(x, Wx, bv, out);
    scan_kernel<<<dim3(B_ / 2), dim3(512), 0, stream>>>(Wh, s0, out);
}

// Round 17
// 1858.933 us; speedup vs baseline: 2.2795x; 1.4811x over previous
//
#include <hip/hip_runtime.h>

#define B_ 16
#define S_ 4096
#define D_ 256
#define H_ 256

typedef _Float16 h2 __attribute__((ext_vector_type(2)));
typedef _Float16 h4 __attribute__((ext_vector_type(4)));
typedef _Float16 h8 __attribute__((ext_vector_type(8)));
typedef _Float16 h8v __attribute__((ext_vector_type(8)));
typedef float f4 __attribute__((ext_vector_type(4)));

static __device__ __forceinline__ float fdot2f(h2 a, h2 b, float c) {
    return __builtin_amdgcn_fdot2(a, b, c, false);
}

template <int CTRL>
static __device__ __forceinline__ float dpp_qp(float v) {
    int r = __builtin_amdgcn_update_dpp(0, __float_as_int(v), CTRL, 0xF, 0xF, true);
    return __int_as_float(r);
}
#define DPP_XOR1 0xB1    // quad_perm [1,0,3,2] : lane ^ 1
#define DPP_XOR2 0x4E    // quad_perm [2,3,0,1] : lane ^ 2
#define DPP_ROR8 0x128   // row_ror:8 == lane ^ 8 within a 16-lane row

// LDS-only barrier: drain LDS ops, NOT vmcnt (T4).
static __device__ __forceinline__ void lds_barrier() {
    asm volatile("s_waitcnt lgkmcnt(0)" ::: "memory");
    __builtin_amdgcn_s_barrier();
}

// swizzled f16-index for h element i (R4/R8-verified layout)
static __device__ __forceinline__ int swz(int i) {
    const int s = i >> 6, r = (i >> 3) & 7, e = i & 7;
    return 64 * s + 8 * ((r + 2 * s) & 7) + e;
}
// f16 base position of 16B chunk c in the swz layout
static __device__ __forceinline__ int swz_chunk(int c) {
    const int s = c >> 3, r = c & 7;
    return 64 * s + 8 * ((r + 2 * s) & 7);
}

// Kernel 1: xp = x @ Wx + b via MFMA f16 (round-14 version, verified).
__global__ __launch_bounds__(256, 1) void xproj_kernel(
    const float* __restrict__ x, const float* __restrict__ Wx,
    const float* __restrict__ bias, float* __restrict__ out)
{
    __shared__ __align__(16) _Float16 xs[16 * 272];
    const int tid = threadIdx.x;
    const int l   = tid & 63;
    const int wav = tid >> 6;
    const int lc  = l & 15;
    const int kg  = l >> 4;
    const long long row0 = (long long)blockIdx.x * 256;

    h8v bf[4][8];
    #pragma unroll
    for (int nt = 0; nt < 4; ++nt) {
        const int j = 64 * wav + 16 * nt + lc;
        #pragma unroll
        for (int ks = 0; ks < 8; ++ks) {
            #pragma unroll
            for (int e = 0; e < 8; ++e)
                bf[nt][ks][e] = (_Float16)Wx[(32 * ks + 8 * kg + e) * H_ + j];
        }
    }
    float bvv[4];
    #pragma unroll
    for (int nt = 0; nt < 4; ++nt)
        bvv[nt] = bias[64 * wav + 16 * nt + lc];

    f4 pre[4];
    #pragma unroll
    for (int k4 = 0; k4 < 4; ++k4)
        pre[k4] = *(const f4*)&x[(row0 + wav + 4 * k4) * D_ + 4 * l];

    for (int it = 0; it < 16; ++it) {
        const long long r0 = row0 + it * 16;

        __syncthreads();
        #pragma unroll
        for (int k4 = 0; k4 < 4; ++k4) {
            h4 hv;
            hv[0] = (_Float16)pre[k4].x;
            hv[1] = (_Float16)pre[k4].y;
            hv[2] = (_Float16)pre[k4].z;
            hv[3] = (_Float16)pre[k4].w;
            *(h4*)&xs[(wav + 4 * k4) * 272 + 4 * l] = hv;
        }
        __syncthreads();

        if (it + 1 < 16) {
            const long long rn = row0 + (it + 1) * 16;
            #pragma unroll
            for (int k4 = 0; k4 < 4; ++k4)
                pre[k4] = *(const f4*)&x[(rn + wav + 4 * k4) * D_ + 4 * l];
        }

        f4 acc[4];
        #pragma unroll
        for (int nt = 0; nt < 4; ++nt)
            acc[nt] = (f4){0.f, 0.f, 0.f, 0.f};

        #pragma unroll
        for (int ks = 0; ks < 8; ++ks) {
            h8v af = *(const h8v*)&xs[lc * 272 + 32 * ks + 8 * kg];
            acc[0] = __builtin_amdgcn_mfma_f32_16x16x32_f16(af, bf[0][ks], acc[0], 0, 0, 0);
            acc[1] = __builtin_amdgcn_mfma_f32_16x16x32_f16(af, bf[1][ks], acc[1], 0, 0, 0);
            acc[2] = __builtin_amdgcn_mfma_f32_16x16x32_f16(af, bf[2][ks], acc[2], 0, 0, 0);
            acc[3] = __builtin_amdgcn_mfma_f32_16x16x32_f16(af, bf[3][ks], acc[3], 0, 0, 0);
        }

        #pragma unroll
        for (int nt = 0; nt < 4; ++nt) {
            const int j = 64 * wav + 16 * nt + lc;
            #pragma unroll
            for (int r = 0; r < 4; ++r)
                out[(r0 + 4 * kg + r) * H_ + j] = acc[nt][r] + bvv[nt];
        }
    }
}

// Kernel 2: WAVE-SPECIALIZED scan. One block (CU) per batch, 512 threads.
// Waves 0-3 (tid<256): cols 0-127 via replicated-row MFMA (matrix pipe).
// Waves 4-7: cols 128-255 via split-K x8 dot2 + DPP reduce (VALU pipe).
// SIMD s hosts wave s (MFMA) + wave s+4 (VALU): pipes co-issue (m114).
// h in R8's swz layout: MFMA reads broadcast, VALU reads 2-way-free,
// publishes = R8 pattern (0 conflicts measured). lgkm-only barrier.
__global__ __launch_bounds__(512, 1) void scan_kernel(
    const float* __restrict__ Wh, const float* __restrict__ state0,
    float* __restrict__ out)
{
    __shared__ __align__(16) _Float16 hbuf[2][H_];
    const int tid0 = threadIdx.x;
    const int b = blockIdx.x;
    float* __restrict__ outb = out + (long long)b * S_ * H_;

    if (tid0 < 256) {
        // ================= MFMA half: cols 0..127 =================
        const int l   = tid0 & 63;
        const int wav = tid0 >> 6;      // 0..3
        const int lc  = l & 15;
        const int kg  = l >> 4;         // 0..3
        const int j_m = 32 * wav + 16 * kg + lc;   // owner col if kg<2
        const bool own = (kg < 2);

        // B-frags (R11 convention): 2 N-tiles, j = 32wav+16nt+lc
        h8v bf[2][8];
        #pragma unroll
        for (int nt = 0; nt < 2; ++nt) {
            const int j = 32 * wav + 16 * nt + lc;
            #pragma unroll
            for (int ks = 0; ks < 8; ++ks) {
                #pragma unroll
                for (int e = 0; e < 8; ++e)
                    bf[nt][ks][e] = (_Float16)Wh[(32 * ks + 8 * kg + e) * H_ + j];
            }
        }
        // A-frag swz addresses: chunk c = 4ks+kg
        int abase[8];
        #pragma unroll
        for (int ks = 0; ks < 8; ++ks)
            abase[ks] = swz_chunk(4 * ks + kg);

        hbuf[0][swz(tid0)] = (_Float16)state0[b * H_ + tid0];

        float xr[4];
        #pragma unroll
        for (int k = 0; k < 4; ++k)
            xr[k] = outb[(long long)k * H_ + j_m];
        __syncthreads();

        #pragma unroll 4
        for (int st = 0; st < S_; ++st) {
            const int p = st & 1;
            const _Float16* hb = hbuf[p];

            f4 acc0 = {0.f, 0.f, 0.f, 0.f};
            f4 acc1 = {0.f, 0.f, 0.f, 0.f};
            #pragma unroll
            for (int ks = 0; ks < 8; ++ks) {
                h8v af = *(const h8v*)&hb[abase[ks]];
                acc0 = __builtin_amdgcn_mfma_f32_16x16x32_f16(af, bf[0][ks], acc0, 0, 0, 0);
                acc1 = __builtin_amdgcn_mfma_f32_16x16x32_f16(af, bf[1][ks], acc1, 0, 0, 0);
            }

            const float v = (kg == 1) ? acc1[0] : acc0[0];
            const float pre = v + xr[st & 3];
            const float e = __builtin_amdgcn_exp2f(pre * 2.8853900817779268f);
            const float hn = fmaf(-2.f, __builtin_amdgcn_rcpf(e + 1.f), 1.f);

            if (own) {
                outb[(long long)st * H_ + j_m] = hn;     // stays in flight
                hbuf[p ^ 1][swz(j_m)] = (_Float16)hn;    // publish for t+1
            }
            const int nt4 = st + 4;
            if (nt4 < S_) xr[st & 3] = outb[(long long)nt4 * H_ + j_m];
            lds_barrier();
        }
    } else {
        // ================= VALU half: cols 128..255 =================
        const int t  = tid0 - 256;                      // 0..255
        const int sl = (t & 3) | ((t >> 1) & 4);        // slice 0..7 (32 i's)
        const int g  = ((t >> 2) & 1) | ((t >> 4) << 1); // group 0..31
        const bool s1 = (sl & 1) != 0, s2 = (sl & 2) != 0;
        const bool own = (t & 8) == 0;
        const int j_v = 128 + 4 * g + (t & 3);

        // W[i][j]: i in [32sl, 32sl+32), j in [128+4g, 128+4g+4)
        h2 w[4][16];
        #pragma unroll
        for (int jj = 0; jj < 4; ++jj) {
            const int j = 128 + 4 * g + jj;
            #pragma unroll
            for (int pp = 0; pp < 16; ++pp) {
                const int i = 32 * sl + 2 * pp;
                h2 q;
                q[0] = (_Float16)Wh[(long long)i * H_ + j];
                q[1] = (_Float16)Wh[(long long)(i + 1) * H_ + j];
                w[jj][pp] = q;
            }
        }
        int raddr[4];
        #pragma unroll
        for (int k = 0; k < 4; ++k)
            raddr[k] = swz_chunk(4 * sl + k);

        float xr[4];
        #pragma unroll
        for (int k = 0; k < 4; ++k)
            xr[k] = outb[(long long)k * H_ + j_v];
        __syncthreads();

        #pragma unroll 4
        for (int st = 0; st < S_; ++st) {
            const int p = st & 1;
            const _Float16* hb = hbuf[p];

            union { h8 v; h2 q[4]; } u[4];
            #pragma unroll
            for (int k = 0; k < 4; ++k)
                u[k].v = *(const h8*)&hb[raddr[k]];

            float a0 = 0.f, a1 = 0.f, a2 = 0.f, a3 = 0.f;
            #pragma unroll
            for (int k = 0; k < 4; ++k) {
                #pragma unroll
                for (int m = 0; m < 4; ++m) {
                    const int ii = 4 * k + m;
                    a0 = fdot2f(u[k].q[m], w[0][ii], a0);
                    a1 = fdot2f(u[k].q[m], w[1][ii], a1);
                    a2 = fdot2f(u[k].q[m], w[2][ii], a2);
                    a3 = fdot2f(u[k].q[m], w[3][ii], a3);
                }
            }

            // 8-way reduce (R10-verified): xor1, xor2, ror8(all-reduce)
            float k0 = s1 ? a1 : a0, d0 = s1 ? a0 : a1;
            float k1 = s1 ? a3 : a2, d1 = s1 ? a2 : a3;
            k0 += dpp_qp<DPP_XOR1>(d0);
            k1 += dpp_qp<DPP_XOR1>(d1);
            float n = s2 ? k1 : k0, e0 = s2 ? k0 : k1;
            n += dpp_qp<DPP_XOR2>(e0);
            n += dpp_qp<DPP_ROR8>(n);
            // n = full dot for j_v (duplicated across t^8 partners)

            const float pre = n + xr[st & 3];
            const float e = __builtin_amdgcn_exp2f(pre * 2.8853900817779268f);
            const float hn = fmaf(-2.f, __builtin_amdgcn_rcpf(e + 1.f), 1.f);

            if (own) {
                outb[(long long)st * H_ + j_v] = hn;
                hbuf[p ^ 1][swz(j_v)] = (_Float16)hn;
            }
            const int nt4 = st + 4;
            if (nt4 < S_) xr[st & 3] = outb[(long long)nt4 * H_ + j_v];
            lds_barrier();
        }
    }
}

extern "C" void kernel_launch(void* const* d_in, const int* in_sizes, int n_in,
                              void* d_out, int out_size, void* d_ws, size_t ws_size,
                              hipStream_t stream) {
    const float* x  = (const float*)d_in[0];   // [B,S,D]
    const float* s0 = (const float*)d_in[1];   // [B,H]
    const float* Wx = (const float*)d_in[2];   // [D,H]
    const float* Wh = (const float*)d_in[3];   // [H,H]
    const float* bv = (const float*)d_in[4];   // [H]
    float* out = (float*)d_out;                // [B,S,H]

    xproj_kernel<<<dim3((B_ * S_) / 256), dim3(256), 0, stream>>>(x, Wx, bv, out);
    scan_kernel<<<dim3(B_), dim3(512), 0, stream>>>(Wh, s0, out);
}